// Round 5
// baseline (836.859 us; speedup 1.0000x reference)
//
#include <hip/hip_runtime.h>

typedef __bf16 bf16;
typedef __bf16 bf16x8 __attribute__((ext_vector_type(8)));
typedef float  f32x4  __attribute__((ext_vector_type(4)));

#define T_STEPS 128
#define BATCH   256
#define HD      1024
#define N4H     4096
#define EMB_D   128

__device__ __forceinline__ float fast_sigmoid(float x) {
    return 1.0f / (1.0f + __expf(-x));
}
__device__ __forceinline__ float fast_tanh(float x) {
    return 1.0f - 2.0f / (__expf(2.0f * x) + 1.0f);
}

// ---------------- prep: P[v][n] = (emb[v] @ Wx_gate)[hcol] + b_gate[hcol],
// n = 4*hcol + gate, gate order (g,i,f,o) ----------------
__global__ void build_P(const float* __restrict__ emb,
                        const float* __restrict__ Wgx, const float* __restrict__ Wix,
                        const float* __restrict__ Wfx, const float* __restrict__ Wox,
                        const float* __restrict__ bg,  const float* __restrict__ bi,
                        const float* __restrict__ bfv, const float* __restrict__ bo,
                        float* __restrict__ P)
{
    int n = blockIdx.x * 256 + threadIdx.x;
    int v  = n >> 12;
    int nn = n & (N4H - 1);
    int hcol = nn >> 2, gate = nn & 3;
    const float* Wx = (gate == 0) ? Wgx : (gate == 1) ? Wix : (gate == 2) ? Wfx : Wox;
    const float* bb = (gate == 0) ? bg  : (gate == 1) ? bi  : (gate == 2) ? bfv : bo;
    float s = bb[hcol];
    for (int e = 0; e < EMB_D; ++e)
        s += emb[v * EMB_D + e] * Wx[e * HD + hcol];
    P[n] = s;
}

// ---------------- prep: WhpT[n][k] = Wh_gate[k][hcol] as bf16 ----------------
__global__ void build_W(const float* __restrict__ Wgh, const float* __restrict__ Wih,
                        const float* __restrict__ Wfh, const float* __restrict__ Woh,
                        bf16* __restrict__ WhpT)
{
    __shared__ float tile[64][65];
    int bid  = blockIdx.x;
    int gate = bid >> 8;
    int t2   = bid & 255;
    int kt = t2 >> 4, ht = t2 & 15;
    const float* W = (gate == 0) ? Wgh : (gate == 1) ? Wih : (gate == 2) ? Wfh : Woh;
    int tid = threadIdx.x;
    #pragma unroll
    for (int it = 0; it < 16; ++it) {
        int idx = it * 256 + tid;
        int kk = idx >> 6, hh = idx & 63;
        tile[kk][hh] = W[(size_t)(kt * 64 + kk) * HD + ht * 64 + hh];
    }
    __syncthreads();
    #pragma unroll
    for (int it = 0; it < 16; ++it) {
        int idx = it * 256 + tid;
        int hh = idx >> 6, kk = idx & 63;
        int n = (ht * 64 + hh) * 4 + gate;
        WhpT[(size_t)n * HD + kt * 64 + kk] = (bf16)tile[kk][hh];
    }
}

// ---------------- main persistent kernel ----------------
// 256 blocks x 512 threads (8 waves), 1 block/CU. Group g = bid>>5 owns batch
// rows [g*32,+32); member j = bid&31 owns gate-cols [j*128,+128). Weights are
// PINNED in VGPRs (asm keep-alive; wave = 32 cols x 512 k split as owned/other
// 16-col halves). Wave (w,kh) OWNS fn=kh: it ships the other fn's partials to
// its partner wave (wid^4) via a stride-9 (conflict-free) LDS exchange, so all
// 8 waves do gates+stores. h via sc0 sc1 (device-coherent point); one relaxed
// atomic arrive per block per step; only tid 0 spins.
__global__ __launch_bounds__(512, 2)
void lstm_main(const int* __restrict__ x, const float* __restrict__ P,
               const bf16* __restrict__ WhpT, bf16* __restrict__ hbuf,
               int* __restrict__ ctl)
{
    __shared__ bf16  Blds[32][1024];     // 64 KB swizzled h tile
    __shared__ float red[8][64][9];      // 18 KB exchange (stride 9 -> conflict-free)

    const int tid  = threadIdx.x;
    const int lane = tid & 63;
    const int wid  = tid >> 6;           // 0..7
    const int w    = wid & 3;            // n-subgroup (32 gate-cols)
    const int kh   = wid >> 2;           // k-half; also the OWNED fn
    const int frow = lane & 15;
    const int kgrp = lane >> 4;
    const int bid  = blockIdx.x;
    const int g    = bid >> 5;           // batch group 0..7
    const int j    = bid & 31;           // col member 0..31

    int* bar = ctl + g * 16;

    // ---- persistent A in registers, split owned-fn / other-fn ----
    const int rowO = j * 128 + w * 32 + kh * 16 + frow;
    const int rowX = j * 128 + w * 32 + (1 - kh) * 16 + frow;
    const bf16* AbO = WhpT + (size_t)rowO * HD + kh * 512 + kgrp * 8;
    const bf16* AbX = WhpT + (size_t)rowX * HD + kh * 512 + kgrp * 8;
    bf16x8 ArO[16], ArX[16];
    #pragma unroll
    for (int ks = 0; ks < 16; ++ks) {
        ArO[ks] = *(const bf16x8*)(AbO + ks * 32);
        ArX[ks] = *(const bf16x8*)(AbX + ks * 32);
    }
    // pin in VGPRs: values now originate from asm -> compiler cannot
    // rematerialize the global loads inside the step loop
    #pragma unroll
    for (int ks = 0; ks < 16; ++ks) {
        asm volatile("" : "+v"(ArO[ks]));
        asm volatile("" : "+v"(ArX[ks]));
    }

    const int mr0 = g * 32 + frow;                       // fm=0 batch row
    const int pnb = j * 128 + w * 32 + kh * 16 + kgrp * 4;  // owned-fn P base
    const int hcb = j * 32 + w * 8 + kh * 4 + kgrp;         // owned-fn h col
    const int xorf = frow & 7;
    char* BB = (char*)&Blds[0][0];
    float* rw = &red[0][0][0] + ((size_t)(wid ^ 4) * 64 + lane) * 9;
    const float* rr = &red[0][0][0] + ((size_t)wid * 64 + lane) * 9;

    float st0 = 0.f, st1 = 0.f;
    f32x4 accP0, accP1;
    {
        int xv0 = x[mr0], xv1 = x[mr0 + 16];
        accP0 = *(const f32x4*)(P + (size_t)xv0 * N4H + pnb);
        accP1 = *(const f32x4*)(P + (size_t)xv1 * N4H + pnb);
    }

    for (int t = 0; t < T_STEPS; ++t) {
        f32x4 accO0 = accP0, accO1 = accP1;             // owned fn (P-seeded)
        f32x4 z = {0.f, 0.f, 0.f, 0.f};
        f32x4 accX0 = z, accX1 = z;                     // other fn (partials)

        if (t > 0) {
            if (tid == 0) {
                const int tgt = 32 * t;
                long guard = 0;
                while (__hip_atomic_load(bar, __ATOMIC_RELAXED, __HIP_MEMORY_SCOPE_AGENT) < tgt
                       && ++guard < (1L << 24)) {}
            }
            __syncthreads();
            // ---- stage 64 KB h tile into swizzled LDS (coherence-point loads) ----
            const char* src = (const char*)(hbuf + (size_t)(t & 1) * BATCH * HD
                                                 + (size_t)g * 32 * HD);
            f32x4 stg[8];
            #pragma unroll
            for (int i2 = 0; i2 < 8; ++i2)
                asm volatile("global_load_dwordx4 %0, %1, off sc0 sc1"
                             : "=v"(stg[i2]) : "v"(src + (i2 * 512 + tid) * 16));
            asm volatile("s_waitcnt vmcnt(0)" ::: "memory");
            #pragma unroll
            for (int i2 = 0; i2 < 8; ++i2) {
                int c = i2 * 512 + tid;
                int row = c >> 7, cg = c & 127;
                *(f32x4*)(BB + row * 2048 + ((cg ^ (row & 7)) << 4)) = stg[i2];
            }
            __syncthreads();
            // ---- GEMM on this wave's k-half; A from pinned regs, B from LDS ----
            #pragma unroll
            for (int ks = 0; ks < 16; ++ks) {
                int off = ((kh * 64 + ks * 4 + kgrp) ^ xorf) << 4;
                bf16x8 b0 = *(const bf16x8*)(BB + frow * 2048 + off);
                bf16x8 b1 = *(const bf16x8*)(BB + (frow + 16) * 2048 + off);
                accO0 = __builtin_amdgcn_mfma_f32_16x16x32_bf16(ArO[ks], b0, accO0, 0, 0, 0);
                accO1 = __builtin_amdgcn_mfma_f32_16x16x32_bf16(ArO[ks], b1, accO1, 0, 0, 0);
                accX0 = __builtin_amdgcn_mfma_f32_16x16x32_bf16(ArX[ks], b0, accX0, 0, 0, 0);
                accX1 = __builtin_amdgcn_mfma_f32_16x16x32_bf16(ArX[ks], b1, accX1, 0, 0, 0);
            }
        }

        // ---- ship other-fn partials to partner wave (stride-9, conflict-free) ----
        rw[0] = accX0[0]; rw[1] = accX0[1]; rw[2] = accX0[2]; rw[3] = accX0[3];
        rw[4] = accX1[0]; rw[5] = accX1[1]; rw[6] = accX1[2]; rw[7] = accX1[3];
        __syncthreads();
        accO0[0] += rr[0]; accO0[1] += rr[1]; accO0[2] += rr[2]; accO0[3] += rr[3];
        accO1[0] += rr[4]; accO1[1] += rr[5]; accO1[2] += rr[6]; accO1[3] += rr[7];

        // ---- gates + state update for the OWNED fn (all 8 waves active) ----
        bf16* hout = hbuf + (size_t)((t + 1) & 1) * BATCH * HD;
        {
            float gg = fast_tanh(accO0[0]);
            float ii = fast_sigmoid(accO0[1]);
            float ff = fast_sigmoid(accO0[2]);
            float oo = fast_sigmoid(accO0[3]);
            float s = gg * ii + st0 * ff;
            st0 = s;
            bf16 hv = (bf16)(fast_tanh(s) * oo);
            unsigned hv32 = (unsigned)__builtin_bit_cast(unsigned short, hv);
            const bf16* hp = hout + (size_t)mr0 * HD + hcb;
            asm volatile("global_store_short %0, %1, off sc0 sc1"
                         :: "v"(hp), "v"(hv32) : "memory");
        }
        {
            float gg = fast_tanh(accO1[0]);
            float ii = fast_sigmoid(accO1[1]);
            float ff = fast_sigmoid(accO1[2]);
            float oo = fast_sigmoid(accO1[3]);
            float s = gg * ii + st1 * ff;
            st1 = s;
            bf16 hv = (bf16)(fast_tanh(s) * oo);
            unsigned hv32 = (unsigned)__builtin_bit_cast(unsigned short, hv);
            const bf16* hp = hout + (size_t)(mr0 + 16) * HD + hcb;
            asm volatile("global_store_short %0, %1, off sc0 sc1"
                         :: "v"(hp), "v"(hv32) : "memory");
        }

        // ---- prefetch next step's x/P (constant data, off critical path) ----
        if (t < T_STEPS - 1) {
            int xv0 = x[(t + 1) * BATCH + mr0], xv1 = x[(t + 1) * BATCH + mr0 + 16];
            accP0 = *(const f32x4*)(P + (size_t)xv0 * N4H + pnb);
            accP1 = *(const f32x4*)(P + (size_t)xv1 * N4H + pnb);
        }

        __syncthreads();   // each thread drains its own h stores before barrier
        if (tid == 0 && t < T_STEPS - 1)
            __hip_atomic_fetch_add(bar, 1, __ATOMIC_RELAXED, __HIP_MEMORY_SCOPE_AGENT);
    }
}

// ---------------- final projection: out[b][c] = h_T[b] @ Wph + bp ----------------
__global__ void proj_out(const bf16* __restrict__ h, const float* __restrict__ Wph,
                         const float* __restrict__ bp, float* __restrict__ out)
{
    __shared__ float red[256][10];
    int b = blockIdx.x, tid = threadIdx.x;
    float acc[10];
    #pragma unroll
    for (int c = 0; c < 10; ++c) acc[c] = 0.f;
    for (int k = tid; k < HD; k += 256) {
        float hv = (float)h[(size_t)b * HD + k];
        #pragma unroll
        for (int c = 0; c < 10; ++c)
            acc[c] += hv * Wph[k * 10 + c];
    }
    #pragma unroll
    for (int c = 0; c < 10; ++c) red[tid][c] = acc[c];
    __syncthreads();
    for (int s = 128; s > 0; s >>= 1) {
        if (tid < s) {
            #pragma unroll
            for (int c = 0; c < 10; ++c) red[tid][c] += red[tid + s][c];
        }
        __syncthreads();
    }
    if (tid < 10) out[b * 10 + tid] = red[0][tid] + bp[tid];
}

extern "C" void kernel_launch(void* const* d_in, const int* in_sizes, int n_in,
                              void* d_out, int out_size, void* d_ws, size_t ws_size,
                              hipStream_t stream)
{
    const int*   x   = (const int*)  d_in[0];
    const float* emb = (const float*)d_in[1];
    const float* Wgx = (const float*)d_in[2];
    const float* Wgh = (const float*)d_in[3];
    const float* Wix = (const float*)d_in[4];
    const float* Wih = (const float*)d_in[5];
    const float* Wfx = (const float*)d_in[6];
    const float* Wfh = (const float*)d_in[7];
    const float* Wox = (const float*)d_in[8];
    const float* Woh = (const float*)d_in[9];
    const float* bg  = (const float*)d_in[10];
    const float* bi  = (const float*)d_in[11];
    const float* bfv = (const float*)d_in[12];
    const float* bo  = (const float*)d_in[13];
    const float* Wph = (const float*)d_in[14];
    const float* bp  = (const float*)d_in[15];

    char* ws = (char*)d_ws;
    bf16*  WhpT = (bf16*)ws;                                   // 8 MB
    float* P    = (float*)(ws + 8388608);                      // 160 KB
    bf16*  hbuf = (bf16*)(ws + 8388608 + 163840);              // 2 x 512 KB
    int*   ctl  = (int*)(ws + 8388608 + 163840 + 1048576);     // 8 groups x 64B

    hipMemsetAsync(ctl, 0, 8 * 16 * sizeof(int), stream);
    build_P<<<160, 256, 0, stream>>>(emb, Wgx, Wix, Wfx, Wox, bg, bi, bfv, bo, P);
    build_W<<<1024, 256, 0, stream>>>(Wgh, Wih, Wfh, Woh, WhpT);

    void* args[] = { (void*)&x, (void*)&P, (void*)&WhpT, (void*)&hbuf, (void*)&ctl };
    hipLaunchCooperativeKernel((void*)lstm_main, dim3(256), dim3(512), args, 0, stream);

    proj_out<<<256, 256, 0, stream>>>(hbuf, Wph, bp, (float*)d_out);
}

// Round 6
// 635.757 us; speedup vs baseline: 1.3163x; 1.3163x over previous
//
#include <hip/hip_runtime.h>

typedef __bf16 bf16;
typedef __bf16 bf16x8 __attribute__((ext_vector_type(8)));
typedef float  f32x4  __attribute__((ext_vector_type(4)));
typedef int    i32x4  __attribute__((ext_vector_type(4)));

#define T_STEPS 128
#define BATCH   256
#define HD      1024
#define N4H     4096
#define EMB_D   128

// MFMA with A-operand pinned in AGPRs (weights), B and acc in VGPRs.
#define MFMA_BF16(acc, Aop, Bop) \
    asm("v_mfma_f32_16x16x32_bf16 %0, %1, %2, %0" : "+v"(acc) : "a"(Aop), "v"(Bop))

__device__ __forceinline__ float fast_sigmoid(float x) {
    return 1.0f / (1.0f + __expf(-x));
}
__device__ __forceinline__ float fast_tanh(float x) {
    return 1.0f - 2.0f / (__expf(2.0f * x) + 1.0f);
}

// ---------------- prep: P[v][n] = (emb[v] @ Wx_gate)[hcol] + b_gate[hcol],
// n = 4*hcol + gate, gate order (g,i,f,o) ----------------
__global__ void build_P(const float* __restrict__ emb,
                        const float* __restrict__ Wgx, const float* __restrict__ Wix,
                        const float* __restrict__ Wfx, const float* __restrict__ Wox,
                        const float* __restrict__ bg,  const float* __restrict__ bi,
                        const float* __restrict__ bfv, const float* __restrict__ bo,
                        float* __restrict__ P)
{
    int n = blockIdx.x * 256 + threadIdx.x;
    int v  = n >> 12;
    int nn = n & (N4H - 1);
    int hcol = nn >> 2, gate = nn & 3;
    const float* Wx = (gate == 0) ? Wgx : (gate == 1) ? Wix : (gate == 2) ? Wfx : Wox;
    const float* bb = (gate == 0) ? bg  : (gate == 1) ? bi  : (gate == 2) ? bfv : bo;
    float s = bb[hcol];
    for (int e = 0; e < EMB_D; ++e)
        s += emb[v * EMB_D + e] * Wx[e * HD + hcol];
    P[n] = s;
}

// ---------------- prep: WhpT[n][k] = Wh_gate[k][hcol] as bf16 ----------------
__global__ void build_W(const float* __restrict__ Wgh, const float* __restrict__ Wih,
                        const float* __restrict__ Wfh, const float* __restrict__ Woh,
                        bf16* __restrict__ WhpT)
{
    __shared__ float tile[64][65];
    int bid  = blockIdx.x;
    int gate = bid >> 8;
    int t2   = bid & 255;
    int kt = t2 >> 4, ht = t2 & 15;
    const float* W = (gate == 0) ? Wgh : (gate == 1) ? Wih : (gate == 2) ? Wfh : Woh;
    int tid = threadIdx.x;
    #pragma unroll
    for (int it = 0; it < 16; ++it) {
        int idx = it * 256 + tid;
        int kk = idx >> 6, hh = idx & 63;
        tile[kk][hh] = W[(size_t)(kt * 64 + kk) * HD + ht * 64 + hh];
    }
    __syncthreads();
    #pragma unroll
    for (int it = 0; it < 16; ++it) {
        int idx = it * 256 + tid;
        int hh = idx >> 6, kk = idx & 63;
        int n = (ht * 64 + hh) * 4 + gate;
        WhpT[(size_t)n * HD + kt * 64 + kk] = (bf16)tile[kk][hh];
    }
}

// ---------------- main persistent kernel ----------------
// 256 blocks x 512 threads (8 waves), 1 block/CU. Group g = bid&7 (XCD-local:
// 32 blocks, one per CU of one XCD) owns batch rows [g*32,+32); member
// j = bid>>3 owns gate-cols [j*128,+128). Weights pinned in AGPRs (asm "a"
// operands; 128 AGPRs/thread). Wave (w,kh) computes k-half kh for both 16-col
// fn halves, OWNS fn=kh, ships the other to partner wave (wid^4) via a
// stride-9 conflict-free LDS exchange. h stores packed via 2 KB LDS stage ->
// one dword sc0 sc1 store per thread. One relaxed atomic arrive per block per
// step; only tid 0 spins.
__global__ __launch_bounds__(512, 2)
void lstm_main(const int* __restrict__ x, const float* __restrict__ P,
               const bf16* __restrict__ WhpT, bf16* __restrict__ hbuf,
               int* __restrict__ ctl)
{
    __shared__ bf16  Blds[32][1024];     // 64 KB swizzled h tile
    __shared__ float red[8][64][9];      // 18 KB exchange (stride 9 -> conflict-free)
    __shared__ bf16  hst[32][34];        // 2.1 KB h-out packing stage

    const int tid  = threadIdx.x;
    const int lane = tid & 63;
    const int wid  = tid >> 6;           // 0..7
    const int w    = wid & 3;            // n-subgroup (32 gate-cols)
    const int kh   = wid >> 2;           // k-half; also the OWNED fn
    const int frow = lane & 15;
    const int kgrp = lane >> 4;
    const int bid  = blockIdx.x;
    const int g    = bid & 7;            // batch group == XCD (heuristic)
    const int j    = bid >> 3;           // col member 0..31

    int* bar = ctl + g * 16;

    // ---- persistent A in AGPRs, split owned-fn / other-fn ----
    const int rowO = j * 128 + w * 32 + kh * 16 + frow;
    const int rowX = j * 128 + w * 32 + (1 - kh) * 16 + frow;
    const bf16* AbO = WhpT + (size_t)rowO * HD + kh * 512 + kgrp * 8;
    const bf16* AbX = WhpT + (size_t)rowX * HD + kh * 512 + kgrp * 8;
    i32x4 ArO[16], ArX[16];
    #pragma unroll
    for (int ks = 0; ks < 16; ++ks) {
        ArO[ks] = *(const i32x4*)(const void*)(AbO + ks * 32);
        ArX[ks] = *(const i32x4*)(const void*)(AbX + ks * 32);
    }
    #pragma unroll
    for (int ks = 0; ks < 16; ++ks)
        asm volatile("" : "+a"(ArO[ks]), "+a"(ArX[ks]));   // force into AGPRs now

    const int mr0 = g * 32 + frow;                          // fm=0 batch row
    const int clc = w * 8 + kh * 4 + kgrp;                  // owned-fn local h col
    const int pnb = j * 128 + clc * 4;                      // owned-fn P base
    const int xorf = frow & 7;
    char* BB = (char*)&Blds[0][0];
    float* rw = &red[0][0][0] + ((size_t)(wid ^ 4) * 64 + lane) * 9;
    const float* rr = &red[0][0][0] + ((size_t)wid * 64 + lane) * 9;

    float st0 = 0.f, st1 = 0.f;
    f32x4 accP0, accP1;
    {
        int xv0 = x[mr0], xv1 = x[mr0 + 16];
        accP0 = *(const f32x4*)(P + (size_t)xv0 * N4H + pnb);
        accP1 = *(const f32x4*)(P + (size_t)xv1 * N4H + pnb);
    }

    for (int t = 0; t < T_STEPS; ++t) {
        f32x4 accO0 = accP0, accO1 = accP1;             // owned fn (P-seeded)
        f32x4 z = {0.f, 0.f, 0.f, 0.f};
        f32x4 accX0 = z, accX1 = z;                     // other fn (partials)

        if (t > 0) {
            if (tid == 0) {
                const int tgt = 32 * t;
                long guard = 0;
                while (__hip_atomic_load(bar, __ATOMIC_RELAXED, __HIP_MEMORY_SCOPE_AGENT) < tgt
                       && ++guard < (1L << 24)) {}
            }
            __syncthreads();
            // ---- stage 64 KB h tile into swizzled LDS (coherence-point loads) ----
            const char* src = (const char*)(hbuf + (size_t)(t & 1) * BATCH * HD
                                                 + (size_t)g * 32 * HD);
            f32x4 stg[8];
            #pragma unroll
            for (int i2 = 0; i2 < 8; ++i2)
                asm volatile("global_load_dwordx4 %0, %1, off sc0 sc1"
                             : "=v"(stg[i2]) : "v"(src + (i2 * 512 + tid) * 16));
            asm volatile("s_waitcnt vmcnt(0)" ::: "memory");
            #pragma unroll
            for (int i2 = 0; i2 < 8; ++i2) {
                int c = i2 * 512 + tid;
                int row = c >> 7, cg = c & 127;
                *(f32x4*)(BB + row * 2048 + ((cg ^ (row & 7)) << 4)) = stg[i2];
            }
            __syncthreads();
            // ---- GEMM on this wave's k-half; A from AGPRs, B from LDS ----
            #pragma unroll
            for (int ks = 0; ks < 16; ++ks) {
                int off = ((kh * 64 + ks * 4 + kgrp) ^ xorf) << 4;
                i32x4 b0 = *(const i32x4*)(BB + frow * 2048 + off);
                i32x4 b1 = *(const i32x4*)(BB + (frow + 16) * 2048 + off);
                MFMA_BF16(accO0, ArO[ks], b0);
                MFMA_BF16(accO1, ArO[ks], b1);
                MFMA_BF16(accX0, ArX[ks], b0);
                MFMA_BF16(accX1, ArX[ks], b1);
            }
        }

        // ---- ship other-fn partials to partner wave (stride-9, conflict-free) ----
        rw[0] = accX0[0]; rw[1] = accX0[1]; rw[2] = accX0[2]; rw[3] = accX0[3];
        rw[4] = accX1[0]; rw[5] = accX1[1]; rw[6] = accX1[2]; rw[7] = accX1[3];
        __syncthreads();
        accO0[0] += rr[0]; accO0[1] += rr[1]; accO0[2] += rr[2]; accO0[3] += rr[3];
        accO1[0] += rr[4]; accO1[1] += rr[5]; accO1[2] += rr[6]; accO1[3] += rr[7];

        // ---- gates + state update for the OWNED fn (all 8 waves active) ----
        {
            float gg = fast_tanh(accO0[0]);
            float ii = fast_sigmoid(accO0[1]);
            float ff = fast_sigmoid(accO0[2]);
            float oo = fast_sigmoid(accO0[3]);
            float s = gg * ii + st0 * ff;
            st0 = s;
            hst[frow][clc] = (bf16)(fast_tanh(s) * oo);
        }
        {
            float gg = fast_tanh(accO1[0]);
            float ii = fast_sigmoid(accO1[1]);
            float ff = fast_sigmoid(accO1[2]);
            float oo = fast_sigmoid(accO1[3]);
            float s = gg * ii + st1 * ff;
            st1 = s;
            hst[frow + 16][clc] = (bf16)(fast_tanh(s) * oo);
        }

        // ---- prefetch next step's x/P (constant data, off critical path) ----
        if (t < T_STEPS - 1) {
            int xv0 = x[(t + 1) * BATCH + mr0], xv1 = x[(t + 1) * BATCH + mr0 + 16];
            accP0 = *(const f32x4*)(P + (size_t)xv0 * N4H + pnb);
            accP1 = *(const f32x4*)(P + (size_t)xv1 * N4H + pnb);
        }

        __syncthreads();
        // ---- packed coalesced h store: one dword per thread ----
        {
            bf16* hout = hbuf + (size_t)((t + 1) & 1) * BATCH * HD;
            int r = tid >> 4, cp = (tid & 15) * 2;
            unsigned lo = (unsigned)__builtin_bit_cast(unsigned short, hst[r][cp]);
            unsigned hi = (unsigned)__builtin_bit_cast(unsigned short, hst[r][cp + 1]);
            unsigned pv = lo | (hi << 16);
            const bf16* hp = hout + (size_t)(g * 32 + r) * HD + j * 32 + cp;
            asm volatile("global_store_dword %0, %1, off sc0 sc1"
                         :: "v"(hp), "v"(pv) : "memory");
        }
        asm volatile("s_waitcnt vmcnt(0)" ::: "memory");   // own stores drained
        __syncthreads();                                    // all waves drained
        if (tid == 0 && t < T_STEPS - 1)
            __hip_atomic_fetch_add(bar, 1, __ATOMIC_RELAXED, __HIP_MEMORY_SCOPE_AGENT);
    }
}

// ---------------- final projection: out[b][c] = h_T[b] @ Wph + bp ----------------
__global__ void proj_out(const bf16* __restrict__ h, const float* __restrict__ Wph,
                         const float* __restrict__ bp, float* __restrict__ out)
{
    __shared__ float red[256][10];
    int b = blockIdx.x, tid = threadIdx.x;
    float acc[10];
    #pragma unroll
    for (int c = 0; c < 10; ++c) acc[c] = 0.f;
    for (int k = tid; k < HD; k += 256) {
        float hv = (float)h[(size_t)b * HD + k];
        #pragma unroll
        for (int c = 0; c < 10; ++c)
            acc[c] += hv * Wph[k * 10 + c];
    }
    #pragma unroll
    for (int c = 0; c < 10; ++c) red[tid][c] = acc[c];
    __syncthreads();
    for (int s = 128; s > 0; s >>= 1) {
        if (tid < s) {
            #pragma unroll
            for (int c = 0; c < 10; ++c) red[tid][c] += red[tid + s][c];
        }
        __syncthreads();
    }
    if (tid < 10) out[b * 10 + tid] = red[0][tid] + bp[tid];
}

extern "C" void kernel_launch(void* const* d_in, const int* in_sizes, int n_in,
                              void* d_out, int out_size, void* d_ws, size_t ws_size,
                              hipStream_t stream)
{
    const int*   x   = (const int*)  d_in[0];
    const float* emb = (const float*)d_in[1];
    const float* Wgx = (const float*)d_in[2];
    const float* Wgh = (const float*)d_in[3];
    const float* Wix = (const float*)d_in[4];
    const float* Wih = (const float*)d_in[5];
    const float* Wfx = (const float*)d_in[6];
    const float* Wfh = (const float*)d_in[7];
    const float* Wox = (const float*)d_in[8];
    const float* Woh = (const float*)d_in[9];
    const float* bg  = (const float*)d_in[10];
    const float* bi  = (const float*)d_in[11];
    const float* bfv = (const float*)d_in[12];
    const float* bo  = (const float*)d_in[13];
    const float* Wph = (const float*)d_in[14];
    const float* bp  = (const float*)d_in[15];

    char* ws = (char*)d_ws;
    bf16*  WhpT = (bf16*)ws;                                   // 8 MB
    float* P    = (float*)(ws + 8388608);                      // 160 KB
    bf16*  hbuf = (bf16*)(ws + 8388608 + 163840);              // 2 x 512 KB
    int*   ctl  = (int*)(ws + 8388608 + 163840 + 1048576);     // 8 groups x 64B

    hipMemsetAsync(ctl, 0, 8 * 16 * sizeof(int), stream);
    build_P<<<160, 256, 0, stream>>>(emb, Wgx, Wix, Wfx, Wox, bg, bi, bfv, bo, P);
    build_W<<<1024, 256, 0, stream>>>(Wgh, Wih, Wfh, Woh, WhpT);

    void* args[] = { (void*)&x, (void*)&P, (void*)&WhpT, (void*)&hbuf, (void*)&ctl };
    hipLaunchCooperativeKernel((void*)lstm_main, dim3(256), dim3(512), args, 0, stream);

    proj_out<<<256, 256, 0, stream>>>(hbuf, Wph, bp, (float*)d_out);
}

// Round 8
// 518.703 us; speedup vs baseline: 1.6134x; 1.2257x over previous
//
#include <hip/hip_runtime.h>

typedef __bf16 bf16;
typedef __bf16 bf16x8 __attribute__((ext_vector_type(8)));
typedef float  f32x4  __attribute__((ext_vector_type(4)));
typedef int    i32x4  __attribute__((ext_vector_type(4)));

#define T_STEPS 128
#define BATCH   256
#define HD      1024
#define N4H     4096
#define EMB_D   128

// MFMA with A-operand pinned in AGPRs (weights), B and acc in VGPRs.
#define MFMA_BF16(acc, Aop, Bop) \
    asm("v_mfma_f32_16x16x32_bf16 %0, %1, %2, %0" : "+v"(acc) : "a"(Aop), "v"(Bop))

__device__ __forceinline__ float fast_sigmoid(float x) {
    return 1.0f / (1.0f + __expf(-x));
}
__device__ __forceinline__ float fast_tanh(float x) {
    return 1.0f - 2.0f / (__expf(2.0f * x) + 1.0f);
}

// ---------------- prep: P[v][n] = (emb[v] @ Wx_gate)[hcol] + b_gate[hcol],
// n = 4*hcol + gate, gate order (g,i,f,o) ----------------
__global__ void build_P(const float* __restrict__ emb,
                        const float* __restrict__ Wgx, const float* __restrict__ Wix,
                        const float* __restrict__ Wfx, const float* __restrict__ Wox,
                        const float* __restrict__ bg,  const float* __restrict__ bi,
                        const float* __restrict__ bfv, const float* __restrict__ bo,
                        float* __restrict__ P)
{
    int n = blockIdx.x * 256 + threadIdx.x;
    int v  = n >> 12;
    int nn = n & (N4H - 1);
    int hcol = nn >> 2, gate = nn & 3;
    const float* Wx = (gate == 0) ? Wgx : (gate == 1) ? Wix : (gate == 2) ? Wfx : Wox;
    const float* bb = (gate == 0) ? bg  : (gate == 1) ? bi  : (gate == 2) ? bfv : bo;
    float s = bb[hcol];
    for (int e = 0; e < EMB_D; ++e)
        s += emb[v * EMB_D + e] * Wx[e * HD + hcol];
    P[n] = s;
}

// ---------------- prep: WhpT[n][k] = Wh_gate[k][hcol] as bf16 ----------------
__global__ void build_W(const float* __restrict__ Wgh, const float* __restrict__ Wih,
                        const float* __restrict__ Wfh, const float* __restrict__ Woh,
                        bf16* __restrict__ WhpT)
{
    __shared__ float tile[64][65];
    int bid  = blockIdx.x;
    int gate = bid >> 8;
    int t2   = bid & 255;
    int kt = t2 >> 4, ht = t2 & 15;
    const float* W = (gate == 0) ? Wgh : (gate == 1) ? Wih : (gate == 2) ? Wfh : Woh;
    int tid = threadIdx.x;
    #pragma unroll
    for (int it = 0; it < 16; ++it) {
        int idx = it * 256 + tid;
        int kk = idx >> 6, hh = idx & 63;
        tile[kk][hh] = W[(size_t)(kt * 64 + kk) * HD + ht * 64 + hh];
    }
    __syncthreads();
    #pragma unroll
    for (int it = 0; it < 16; ++it) {
        int idx = it * 256 + tid;
        int hh = idx >> 6, kk = idx & 63;
        int n = (ht * 64 + hh) * 4 + gate;
        WhpT[(size_t)n * HD + kt * 64 + kk] = (bf16)tile[kk][hh];
    }
}

// ---------------- main persistent kernel ----------------
// 256 blocks x 512 threads (8 waves), 1 block/CU (LDS-forced). Group g = the
// block's physical XCD (HW_REG_XCC_ID); membership j from an agent-scope
// ticket counter -> exactly 32 blocks/XCD by pigeonhole. h data exchange is
// XCD-L2-local: plain write-back stores, sc0 (L1-bypass) staging loads.
// Control path stays at proven IF scope: __hip_atomic AGENT builtins, with
// the group barrier split over 8 cache lines (4 adds each) to kill same-line
// atomic serialization. Weights pinned in AGPRs; wave (w,kh) owns fn=kh and
// ships the other fn's partials to partner (wid^4) via stride-9 LDS.
__global__ __launch_bounds__(512, 2)
void lstm_main(const int* __restrict__ x, const float* __restrict__ P,
               const bf16* __restrict__ WhpT, bf16* __restrict__ hbuf,
               int* __restrict__ ctl)
{
    __shared__ bf16  Blds[32][1024];     // 64 KB swizzled h tile
    __shared__ float red[8][64][9];      // 18 KB exchange (stride 9 -> conflict-free)
    __shared__ bf16  hst[32][34];        // 2.1 KB h-out packing stage
    __shared__ int   sj;

    const int tid  = threadIdx.x;
    const int lane = tid & 63;
    const int wid  = tid >> 6;           // 0..7
    const int w    = wid & 3;            // n-subgroup (32 gate-cols)
    const int kh   = wid >> 2;           // k-half; also the OWNED fn
    const int frow = lane & 15;
    const int kgrp = lane >> 4;

    // ---- XCD-local group election (agent-scope ticket, IF-coherent) ----
    int xcc;
    asm("s_getreg_b32 %0, hwreg(HW_REG_XCC_ID)" : "=s"(xcc));
    const int g = xcc & 7;               // group == physical XCD
    if (tid == 0)
        sj = __hip_atomic_fetch_add(ctl + 1024 + g * 16, 1,
                                    __ATOMIC_RELAXED, __HIP_MEMORY_SCOPE_AGENT) & 31;
    __syncthreads();
    const int j = sj;                    // member 0..31 within the XCD
    int* bar = ctl + g * 128;            // 8 sub-counters, 64 B apart

    // ---- persistent A in AGPRs, split owned-fn / other-fn ----
    const int rowO = j * 128 + w * 32 + kh * 16 + frow;
    const int rowX = j * 128 + w * 32 + (1 - kh) * 16 + frow;
    const bf16* AbO = WhpT + (size_t)rowO * HD + kh * 512 + kgrp * 8;
    const bf16* AbX = WhpT + (size_t)rowX * HD + kh * 512 + kgrp * 8;
    i32x4 ArO[16], ArX[16];
    #pragma unroll
    for (int ks = 0; ks < 16; ++ks) {
        ArO[ks] = *(const i32x4*)(const void*)(AbO + ks * 32);
        ArX[ks] = *(const i32x4*)(const void*)(AbX + ks * 32);
    }
    #pragma unroll
    for (int ks = 0; ks < 16; ++ks)
        asm volatile("" : "+a"(ArO[ks]), "+a"(ArX[ks]));   // force into AGPRs now

    const int mr0 = g * 32 + frow;                          // fm=0 batch row
    const int clc = w * 8 + kh * 4 + kgrp;                  // owned-fn local h col
    const int pnb = j * 128 + clc * 4;                      // owned-fn P base
    const int xorf = frow & 7;
    char* BB = (char*)&Blds[0][0];
    float* rw = &red[0][0][0] + ((size_t)(wid ^ 4) * 64 + lane) * 9;
    const float* rr = &red[0][0][0] + ((size_t)wid * 64 + lane) * 9;

    float st0 = 0.f, st1 = 0.f;
    f32x4 accP0, accP1;
    {
        int xv0 = x[mr0], xv1 = x[mr0 + 16];
        accP0 = *(const f32x4*)(P + (size_t)xv0 * N4H + pnb);
        accP1 = *(const f32x4*)(P + (size_t)xv1 * N4H + pnb);
    }

    for (int t = 0; t < T_STEPS; ++t) {
        f32x4 accO0 = accP0, accO1 = accP1;             // owned fn (P-seeded)
        f32x4 z = {0.f, 0.f, 0.f, 0.f};
        f32x4 accX0 = z, accX1 = z;                     // other fn (partials)

        if (t > 0) {
            if (tid == 0) {
                const int tgt = 32 * t;
                long guard = 0;
                int sum;
                do {
                    sum = 0;
                    #pragma unroll
                    for (int s8 = 0; s8 < 8; ++s8)
                        sum += __hip_atomic_load(bar + s8 * 16, __ATOMIC_RELAXED,
                                                 __HIP_MEMORY_SCOPE_AGENT);
                } while (sum < tgt && ++guard < (1L << 22));
            }
            __syncthreads();
            // ---- stage 64 KB h tile into swizzled LDS (XCD-local L2 reads) ----
            const char* src = (const char*)(hbuf + (size_t)(t & 1) * BATCH * HD
                                                 + (size_t)g * 32 * HD);
            f32x4 stg[8];
            #pragma unroll
            for (int i2 = 0; i2 < 8; ++i2)
                asm volatile("global_load_dwordx4 %0, %1, off sc0"
                             : "=v"(stg[i2]) : "v"(src + (i2 * 512 + tid) * 16));
            asm volatile("s_waitcnt vmcnt(0)" ::: "memory");
            #pragma unroll
            for (int i2 = 0; i2 < 8; ++i2) {
                int c = i2 * 512 + tid;
                int row = c >> 7, cg = c & 127;
                *(f32x4*)(BB + row * 2048 + ((cg ^ (row & 7)) << 4)) = stg[i2];
            }
            __syncthreads();
            // ---- GEMM on this wave's k-half; A from AGPRs, B from LDS ----
            #pragma unroll
            for (int ks = 0; ks < 16; ++ks) {
                int off = ((kh * 64 + ks * 4 + kgrp) ^ xorf) << 4;
                i32x4 b0 = *(const i32x4*)(BB + frow * 2048 + off);
                i32x4 b1 = *(const i32x4*)(BB + (frow + 16) * 2048 + off);
                MFMA_BF16(accO0, ArO[ks], b0);
                MFMA_BF16(accO1, ArO[ks], b1);
                MFMA_BF16(accX0, ArX[ks], b0);
                MFMA_BF16(accX1, ArX[ks], b1);
            }
        }

        // ---- ship other-fn partials to partner wave (stride-9, conflict-free) ----
        rw[0] = accX0[0]; rw[1] = accX0[1]; rw[2] = accX0[2]; rw[3] = accX0[3];
        rw[4] = accX1[0]; rw[5] = accX1[1]; rw[6] = accX1[2]; rw[7] = accX1[3];
        __syncthreads();
        accO0[0] += rr[0]; accO0[1] += rr[1]; accO0[2] += rr[2]; accO0[3] += rr[3];
        accO1[0] += rr[4]; accO1[1] += rr[5]; accO1[2] += rr[6]; accO1[3] += rr[7];

        // ---- gates + state update for the OWNED fn (all 8 waves active) ----
        {
            float gg = fast_tanh(accO0[0]);
            float ii = fast_sigmoid(accO0[1]);
            float ff = fast_sigmoid(accO0[2]);
            float oo = fast_sigmoid(accO0[3]);
            float s = gg * ii + st0 * ff;
            st0 = s;
            hst[frow][clc] = (bf16)(fast_tanh(s) * oo);
        }
        {
            float gg = fast_tanh(accO1[0]);
            float ii = fast_sigmoid(accO1[1]);
            float ff = fast_sigmoid(accO1[2]);
            float oo = fast_sigmoid(accO1[3]);
            float s = gg * ii + st1 * ff;
            st1 = s;
            hst[frow + 16][clc] = (bf16)(fast_tanh(s) * oo);
        }

        // ---- prefetch next step's x/P (constant data, off critical path) ----
        if (t < T_STEPS - 1) {
            int xv0 = x[(t + 1) * BATCH + mr0], xv1 = x[(t + 1) * BATCH + mr0 + 16];
            accP0 = *(const f32x4*)(P + (size_t)xv0 * N4H + pnb);
            accP1 = *(const f32x4*)(P + (size_t)xv1 * N4H + pnb);
        }

        __syncthreads();
        // ---- packed h store: one plain write-back dword per thread (L2-local) ----
        {
            bf16* hout = hbuf + (size_t)((t + 1) & 1) * BATCH * HD;
            int r = tid >> 4, cp = (tid & 15) * 2;
            unsigned lo = (unsigned)__builtin_bit_cast(unsigned short, hst[r][cp]);
            unsigned hi = (unsigned)__builtin_bit_cast(unsigned short, hst[r][cp + 1]);
            unsigned pv = lo | (hi << 16);
            *(unsigned*)(hout + (size_t)(g * 32 + r) * HD + j * 32 + cp) = pv;
        }
        __syncthreads();   // every wave drains its own stores (vmcnt) at the barrier
        if (tid == 0 && t < T_STEPS - 1)
            __hip_atomic_fetch_add(bar + (j & 7) * 16, 1,
                                   __ATOMIC_RELAXED, __HIP_MEMORY_SCOPE_AGENT);
    }
}

// ---------------- final projection: out[b][c] = h_T[b] @ Wph + bp ----------------
__global__ void proj_out(const bf16* __restrict__ h, const float* __restrict__ Wph,
                         const float* __restrict__ bp, float* __restrict__ out)
{
    __shared__ float red[256][10];
    int b = blockIdx.x, tid = threadIdx.x;
    float acc[10];
    #pragma unroll
    for (int c = 0; c < 10; ++c) acc[c] = 0.f;
    for (int k = tid; k < HD; k += 256) {
        float hv = (float)h[(size_t)b * HD + k];
        #pragma unroll
        for (int c = 0; c < 10; ++c)
            acc[c] += hv * Wph[k * 10 + c];
    }
    #pragma unroll
    for (int c = 0; c < 10; ++c) red[tid][c] = acc[c];
    __syncthreads();
    for (int s = 128; s > 0; s >>= 1) {
        if (tid < s) {
            #pragma unroll
            for (int c = 0; c < 10; ++c) red[tid][c] += red[tid + s][c];
        }
        __syncthreads();
    }
    if (tid < 10) out[b * 10 + tid] = red[0][tid] + bp[tid];
}

extern "C" void kernel_launch(void* const* d_in, const int* in_sizes, int n_in,
                              void* d_out, int out_size, void* d_ws, size_t ws_size,
                              hipStream_t stream)
{
    const int*   x   = (const int*)  d_in[0];
    const float* emb = (const float*)d_in[1];
    const float* Wgx = (const float*)d_in[2];
    const float* Wgh = (const float*)d_in[3];
    const float* Wix = (const float*)d_in[4];
    const float* Wih = (const float*)d_in[5];
    const float* Wfx = (const float*)d_in[6];
    const float* Wfh = (const float*)d_in[7];
    const float* Wox = (const float*)d_in[8];
    const float* Woh = (const float*)d_in[9];
    const float* bg  = (const float*)d_in[10];
    const float* bi  = (const float*)d_in[11];
    const float* bfv = (const float*)d_in[12];
    const float* bo  = (const float*)d_in[13];
    const float* Wph = (const float*)d_in[14];
    const float* bp  = (const float*)d_in[15];

    char* ws = (char*)d_ws;
    bf16*  WhpT = (bf16*)ws;                                   // 8 MB
    float* P    = (float*)(ws + 8388608);                      // 160 KB
    bf16*  hbuf = (bf16*)(ws + 8388608 + 163840);              // 2 x 512 KB
    int*   ctl  = (int*)(ws + 8388608 + 163840 + 1048576);     // bar[8x8 lines]+elect

    hipMemsetAsync(ctl, 0, 8192, stream);                      // covers bar + election
    build_P<<<160, 256, 0, stream>>>(emb, Wgx, Wix, Wfx, Wox, bg, bi, bfv, bo, P);
    build_W<<<1024, 256, 0, stream>>>(Wgh, Wih, Wfh, Woh, WhpT);

    void* args[] = { (void*)&x, (void*)&P, (void*)&WhpT, (void*)&hbuf, (void*)&ctl };
    hipLaunchCooperativeKernel((void*)lstm_main, dim3(256), dim3(512), args, 0, stream);

    proj_out<<<256, 256, 0, stream>>>(hbuf, Wph, bp, (float*)d_out);
}